// Round 3
// baseline (1310.581 us; speedup 1.0000x reference)
//
#include <hip/hip_runtime.h>
#include <hip/hip_bf16.h>

#define LL 4096
#define DD 1024
#define NB 4
#define NFFT 8192
#define LOGN 13
#define KBINS 4097
#define PI_F 3.14159265358979323846f

typedef __attribute__((ext_vector_type(4))) float f32x4;
typedef __attribute__((ext_vector_type(8))) short s16x8;

__device__ __forceinline__ unsigned short f2bf(float f) {
  unsigned int x = __float_as_uint(f);
  x += 0x7fffu + ((x >> 16) & 1u);
  return (unsigned short)(x >> 16);
}

// ---------------------------------------------------------------- twiddles
__global__ void k_twiddle(float2* tw) {
  int k = blockIdx.x * 256 + threadIdx.x;
  if (k < NFFT / 2) {
    float ang = -2.0f * PI_F * (float)k / (float)NFFT;
    float s, c;
    sincosf(ang, &s, &c);
    tw[k] = make_float2(c, s);  // e^{-2pi i k / N}
  }
}

// --------------------------------------------------- shared 8192-pt FFT (256 thr)
__device__ __forceinline__ void fft8192(float* re, float* im,
                                        const float2* __restrict__ tw, bool inv) {
  const int tid = threadIdx.x;
  // bit reversal (13 bits)
  for (int t = tid; t < NFFT; t += 256) {
    int r = (int)(__brev((unsigned)t) >> (32 - LOGN));
    if (r > t) {
      float ar = re[t], ai = im[t];
      re[t] = re[r]; im[t] = im[r];
      re[r] = ar;    im[r] = ai;
    }
  }
  __syncthreads();
  for (int s = 1; s <= LOGN; ++s) {
    const int half = 1 << (s - 1);
    for (int t = tid; t < NFFT / 2; t += 256) {
      int j  = t & (half - 1);
      int p1 = ((t >> (s - 1)) << s) + j;
      int p2 = p1 + half;
      float2 w = tw[j << (LOGN - s)];
      float wr = w.x, wi = inv ? -w.y : w.y;
      float vr = re[p2], vi = im[p2];
      float tr = vr * wr - vi * wi;
      float ti = vr * wi + vi * wr;
      float ur = re[p1], ui = im[p1];
      re[p1] = ur + tr; im[p1] = ui + ti;
      re[p2] = ur - tr; im[p2] = ui - ti;
    }
    __syncthreads();
  }
}

// ------------------------------------------- LN1 + 3-channel projection (wave/row)
__global__ __launch_bounds__(256) void k_ln_proj(
    const float* __restrict__ u, const float* __restrict__ n1w, const float* __restrict__ n1b,
    const float* __restrict__ pw, const float* __restrict__ pb,
    float* __restrict__ xp0, float* __restrict__ xp1, float* __restrict__ xpL) {
  const int wid = threadIdx.x >> 6, lane = threadIdx.x & 63;
  const int r = blockIdx.x * 4 + wid;  // row in [0, NB*LL)
  const float* ur = u + (size_t)r * DD;
  float4 uv[4];
  float s = 0.f, sq = 0.f;
#pragma unroll
  for (int c = 0; c < 4; ++c) {
    uv[c] = ((const float4*)ur)[lane + 64 * c];
    s  += uv[c].x + uv[c].y + uv[c].z + uv[c].w;
    sq += uv[c].x * uv[c].x + uv[c].y * uv[c].y + uv[c].z * uv[c].z + uv[c].w * uv[c].w;
  }
  for (int m = 1; m < 64; m <<= 1) { s += __shfl_xor(s, m); sq += __shfl_xor(sq, m); }
  const float mean = s * (1.0f / DD);
  const float var  = sq * (1.0f / DD) - mean * mean;
  const float rs   = rsqrtf(var + 1e-5f);
  float d0 = 0.f, d1 = 0.f, dL = 0.f;
  const float* pwL = pw + (size_t)3071 * DD;
#pragma unroll
  for (int c = 0; c < 4; ++c) {
    int i4 = lane + 64 * c;
    float4 wv  = ((const float4*)n1w)[i4];
    float4 bv  = ((const float4*)n1b)[i4];
    float4 p0  = ((const float4*)pw)[i4];
    float4 p1v = ((const float4*)(pw + DD))[i4];
    float4 pLv = ((const float4*)pwL)[i4];
    float xn;
    xn = (uv[c].x - mean) * rs * wv.x + bv.x; d0 += xn * p0.x; d1 += xn * p1v.x; dL += xn * pLv.x;
    xn = (uv[c].y - mean) * rs * wv.y + bv.y; d0 += xn * p0.y; d1 += xn * p1v.y; dL += xn * pLv.y;
    xn = (uv[c].z - mean) * rs * wv.z + bv.z; d0 += xn * p0.z; d1 += xn * p1v.z; dL += xn * pLv.z;
    xn = (uv[c].w - mean) * rs * wv.w + bv.w; d0 += xn * p0.w; d1 += xn * p1v.w; dL += xn * pLv.w;
  }
  for (int m = 1; m < 64; m <<= 1) {
    d0 += __shfl_xor(d0, m); d1 += __shfl_xor(d1, m); dL += __shfl_xor(dL, m);
  }
  if (lane == 0) {
    xp0[r] = d0 + pb[0];
    xp1[r] = d1 + pb[1];
    xpL[r] = dL + pb[3071];
  }
}

// ------------------------------------------------------- 3-tap causal depthwise conv
__global__ __launch_bounds__(256) void k_tapconv(
    const float* __restrict__ xp0, const float* __restrict__ xp1, const float* __restrict__ xpL,
    const float* __restrict__ cw, const float* __restrict__ cb,
    float* __restrict__ x0c, float* __restrict__ x1c, float* __restrict__ xLc) {
  int idx = blockIdx.x * 256 + threadIdx.x;
  if (idx >= NB * LL) return;
  int l = idx & (LL - 1);
  int base = idx - l;
  {
    const float* a = xp0 + base;
    float v = cw[2] * a[l];
    if (l >= 1) v += cw[1] * a[l - 1];
    if (l >= 2) v += cw[0] * a[l - 2];
    x0c[idx] = v + cb[0];
  }
  {
    const float* a = xp1 + base;
    float v = cw[5] * a[l];
    if (l >= 1) v += cw[4] * a[l - 1];
    if (l >= 2) v += cw[3] * a[l - 2];
    x1c[idx] = v + cb[1];
  }
  {
    const float* a = xpL + base;
    float v = cw[3071 * 3 + 2] * a[l];
    if (l >= 1) v += cw[3071 * 3 + 1] * a[l - 1];
    if (l >= 2) v += cw[3071 * 3 + 0] * a[l - 2];
    xLc[idx] = v + cb[3071];
  }
}

// ---------------------- SIREN FFN hidden states only -> hid2T[64][LL]  (1 MB)
__global__ __launch_bounds__(256) void k_ffn_hidden(
    const float* __restrict__ pos_z,
    const float* __restrict__ w0, const float* __restrict__ b0, const float* __restrict__ f0,
    const float* __restrict__ w1, const float* __restrict__ b1, const float* __restrict__ f1,
    const float* __restrict__ w2, const float* __restrict__ b2, const float* __restrict__ f2,
    float* __restrict__ hid2T) {
  __shared__ float zin[4][66];
  __shared__ float hbuf[4][64];
  const int g = threadIdx.x >> 6, lane = threadIdx.x & 63;
  const int l0 = blockIdx.x * 16;
  for (int it = 0; it < 4; ++it) {
    const int l = l0 + g * 4 + it;
    zin[g][lane] = pos_z[(size_t)l * 65 + lane];
    if (lane == 0) zin[g][64] = pos_z[(size_t)l * 65 + 64];
    __syncthreads();
    float acc = b0[lane];
#pragma unroll
    for (int k = 0; k < 65; ++k) acc += zin[g][k] * w0[lane * 65 + k];
    float hv = sinf(f0[lane] * acc);
    __syncthreads();
    hbuf[g][lane] = hv;
    __syncthreads();
    acc = b1[lane];
#pragma unroll
    for (int k = 0; k < 64; ++k) acc += hbuf[g][k] * w1[lane * 64 + k];
    hv = sinf(f1[lane] * acc);
    __syncthreads();
    hbuf[g][lane] = hv;
    __syncthreads();
    acc = b2[lane];
#pragma unroll
    for (int k = 0; k < 64; ++k) acc += hbuf[g][k] * w2[lane * 64 + k];
    hv = sinf(f2[lane] * acc);
    hid2T[(size_t)lane * LL + l] = hv;   // transposed store: consumer is coalesced
    __syncthreads();
  }
}

// ----- filter gen (wout proj + decay) fused with forward FFT -> spectra (two-for-one)
__global__ __launch_bounds__(256) void k_fft_filters(
    const float* __restrict__ hid2T, const float* __restrict__ wout,
    const float* __restrict__ alphas, const float* __restrict__ pos_t,
    float2* __restrict__ Hs, const float2* __restrict__ tw) {
  __shared__ float re[NFFT];
  __shared__ float im[NFFT];
  const int i = blockIdx.x >> 9, c = blockIdx.x & 511;
  const int d = 2 * c, e = d + 1;
  const float* wd = wout + (size_t)(i * DD + d) * 64;
  const float* we = wd + 64;
  const float ad = alphas[d], ae = alphas[e];
  for (int l = threadIdx.x; l < LL; l += 256) {
    float accd = 0.f, acce = 0.f;
#pragma unroll
    for (int k = 0; k < 64; ++k) {
      float hk = hid2T[(size_t)k * LL + l];
      accd += hk * wd[k];
      acce += hk * we[k];
    }
    float t = pos_t[l];
    re[l] = accd * expf(ad * t);
    im[l] = acce * expf(ae * t);
  }
  for (int n = LL + threadIdx.x; n < NFFT; n += 256) { re[n] = 0.f; im[n] = 0.f; }
  __syncthreads();
  fft8192(re, im, tw, false);
  float2* Ha = Hs + ((size_t)i * DD + d) * KBINS;
  float2* Hb = Hs + ((size_t)i * DD + e) * KBINS;
  for (int k = threadIdx.x; k < KBINS; k += 256) {
    int m = (NFFT - k) & (NFFT - 1);
    float xr = re[k], xi = im[k], yr = re[m], yi = im[m];
    Ha[k] = make_float2(0.5f * (xr + yr), 0.5f * (xi - yi));
    Hb[k] = make_float2(0.5f * (xi + yi), 0.5f * (yr - xr));
  }
}

// --------------------------------------------------- forward FFT of v0 (4 signals, paired)
__global__ __launch_bounds__(256) void k_fft_v0(const float* __restrict__ xLc,
                                                float2* __restrict__ V0s,
                                                const float2* __restrict__ tw) {
  __shared__ float re[NFFT];
  __shared__ float im[NFFT];
  const int b0 = 2 * blockIdx.x, b1 = b0 + 1;
  const float* a = xLc + (size_t)b0 * LL;
  const float* b = xLc + (size_t)b1 * LL;
  for (int n = threadIdx.x; n < LL; n += 256) { re[n] = a[n]; im[n] = b[n]; }
  for (int n = LL + threadIdx.x; n < NFFT; n += 256) { re[n] = 0.f; im[n] = 0.f; }
  __syncthreads();
  fft8192(re, im, tw, false);
  float2* Va = V0s + (size_t)b0 * KBINS;
  float2* Vb = V0s + (size_t)b1 * KBINS;
  for (int k = threadIdx.x; k < KBINS; k += 256) {
    int m = (NFFT - k) & (NFFT - 1);
    float xr = re[k], xi = im[k], yr = re[m], yi = im[m];
    Va[k] = make_float2(0.5f * (xr + yr), 0.5f * (xi - yi));
    Vb[k] = make_float2(0.5f * (xi + yi), 0.5f * (yr - xr));
  }
}

// ------------------- conv1: product spectra -> packed inverse FFT -> bias + gate -> v1
__global__ __launch_bounds__(256) void k_conv1(
    const float2* __restrict__ Hs0, const float2* __restrict__ V0s,
    const float* __restrict__ x0c, const float* __restrict__ xLc,
    const float* __restrict__ hyb0, float* __restrict__ v1, const float2* __restrict__ tw) {
  __shared__ float re[NFFT];
  __shared__ float im[NFFT];
  const int b = blockIdx.x >> 9, c = blockIdx.x & 511;
  const int d = 2 * c, e = d + 1;
  const float2* Hd = Hs0 + (size_t)d * KBINS;
  const float2* He = Hs0 + (size_t)e * KBINS;
  const float2* V  = V0s + (size_t)b * KBINS;
  for (int k = threadIdx.x; k < KBINS; k += 256) {
    float2 v = V[k], hd = Hd[k], he = He[k];
    float pr = v.x * hd.x - v.y * hd.y, pi = v.x * hd.y + v.y * hd.x;
    float qr = v.x * he.x - v.y * he.y, qi = v.x * he.y + v.y * he.x;
    re[k] = pr - qi; im[k] = pi + qr;
    if (k > 0 && k < NFFT / 2) { re[NFFT - k] = pr + qi; im[NFFT - k] = qr - pi; }
  }
  __syncthreads();
  fft8192(re, im, tw, true);
  const float bd = hyb0[d], be = hyb0[e];
  float* vd = v1 + ((size_t)b * DD + d) * LL;
  float* ve = v1 + ((size_t)b * DD + e) * LL;
  const float* g  = x0c + (size_t)b * LL;
  const float* v0 = xLc + (size_t)b * LL;
  const float inv = 1.0f / NFFT;
  for (int n = threadIdx.x; n < LL; n += 256) {
    float vv = v0[n], gg = g[n];
    vd[n] = gg * (re[n] * inv + bd * vv);
    ve[n] = gg * (im[n] * inv + be * vv);
  }
}

// ----- conv2: fwd FFT (two-for-one) -> product -> packed inverse -> bias + gate (in place)
__global__ __launch_bounds__(256) void k_conv2(
    const float2* __restrict__ Hs1, const float* __restrict__ x1c,
    float* __restrict__ v1, const float* __restrict__ hyb1, const float2* __restrict__ tw) {
  __shared__ float re[NFFT];
  __shared__ float im[NFFT];
  const int b = blockIdx.x >> 9, c = blockIdx.x & 511;
  const int d = 2 * c, e = d + 1;
  float* vd = v1 + ((size_t)b * DD + d) * LL;
  float* ve = v1 + ((size_t)b * DD + e) * LL;
  for (int n = threadIdx.x; n < LL; n += 256) { re[n] = vd[n]; im[n] = ve[n]; }
  for (int n = LL + threadIdx.x; n < NFFT; n += 256) { re[n] = 0.f; im[n] = 0.f; }
  __syncthreads();
  fft8192(re, im, tw, false);
  const float2* Hd = Hs1 + (size_t)d * KBINS;
  const float2* He = Hs1 + (size_t)e * KBINS;
  // separate + multiply + repack; each thread owns slots {k, N-k} exclusively
  for (int k = threadIdx.x; k < KBINS; k += 256) {
    int m = (NFFT - k) & (NFFT - 1);
    float xr = re[k], xi = im[k], yr = re[m], yi = im[m];
    float ar = 0.5f * (xr + yr), ai = 0.5f * (xi - yi);
    float br = 0.5f * (xi + yi), bi = 0.5f * (yr - xr);
    float2 hd = Hd[k], he = He[k];
    float pr = ar * hd.x - ai * hd.y, pi = ar * hd.y + ai * hd.x;
    float qr = br * he.x - bi * he.y, qi = br * he.y + bi * he.x;
    re[k] = pr - qi; im[k] = pi + qr;
    if (k > 0 && k < NFFT / 2) { re[m] = pr + qi; im[m] = qr - pi; }
  }
  __syncthreads();
  fft8192(re, im, tw, true);
  const float bd = hyb1[d], be = hyb1[e];
  const float* g = x1c + (size_t)b * LL;
  const float inv = 1.0f / NFFT;
  for (int n = threadIdx.x; n < LL; n += 256) {
    float vvd = vd[n], vve = ve[n], gg = g[n];
    vd[n] = gg * (re[n] * inv + bd * vvd);
    ve[n] = gg * (im[n] * inv + be * vve);
  }
}

// -------------------------------------------- y[b][l][d] = u + v2^T (LDS tile transpose)
__global__ __launch_bounds__(256) void k_transpose_add(const float* __restrict__ v2,
                                                       const float* __restrict__ u,
                                                       float* __restrict__ y) {
  __shared__ float T[64][65];
  const int bid = blockIdx.x;
  const int lt = bid & 63, dt = (bid >> 6) & 15, b = bid >> 10;
  const int t = threadIdx.x;
  const int tdr = t >> 2, lc0 = (t & 3) * 16;
  const float* vp = v2 + ((size_t)(b * DD + dt * 64 + tdr)) * LL + lt * 64 + lc0;
#pragma unroll
  for (int q = 0; q < 4; ++q) {
    float4 vv = ((const float4*)vp)[q];
    T[tdr][lc0 + 4 * q + 0] = vv.x;
    T[tdr][lc0 + 4 * q + 1] = vv.y;
    T[tdr][lc0 + 4 * q + 2] = vv.z;
    T[tdr][lc0 + 4 * q + 3] = vv.w;
  }
  __syncthreads();
  const int dc = t & 63, lg = t >> 6;
#pragma unroll
  for (int lr0 = 0; lr0 < 64; lr0 += 4) {
    int lr = lr0 + lg;
    size_t idx = ((size_t)b * LL + lt * 64 + lr) * DD + dt * 64 + dc;
    y[idx] = u[idx] + T[dc][lr];
  }
}

// ----------------------------------------------------- LN2 -> bf16 (wave per row)
__global__ __launch_bounds__(256) void k_ln2(const float* __restrict__ y,
                                             const float* __restrict__ w,
                                             const float* __restrict__ bb,
                                             unsigned short* __restrict__ yln) {
  const int wid = threadIdx.x >> 6, lane = threadIdx.x & 63;
  const size_t r = (size_t)blockIdx.x * 4 + wid;
  const float* yr = y + r * DD;
  float4 v[4];
  float s = 0.f, sq = 0.f;
#pragma unroll
  for (int c = 0; c < 4; ++c) {
    v[c] = ((const float4*)yr)[lane + 64 * c];
    s  += v[c].x + v[c].y + v[c].z + v[c].w;
    sq += v[c].x * v[c].x + v[c].y * v[c].y + v[c].z * v[c].z + v[c].w * v[c].w;
  }
  for (int m = 1; m < 64; m <<= 1) { s += __shfl_xor(s, m); sq += __shfl_xor(sq, m); }
  const float mean = s * (1.0f / DD);
  const float var  = sq * (1.0f / DD) - mean * mean;
  const float rs   = rsqrtf(var + 1e-5f);
#pragma unroll
  for (int c = 0; c < 4; ++c) {
    int i4 = lane + 64 * c;
    float4 wv = ((const float4*)w)[i4];
    float4 bv = ((const float4*)bb)[i4];
    ushort4 o;
    o.x = f2bf((v[c].x - mean) * rs * wv.x + bv.x);
    o.y = f2bf((v[c].y - mean) * rs * wv.y + bv.y);
    o.z = f2bf((v[c].z - mean) * rs * wv.z + bv.z);
    o.w = f2bf((v[c].w - mean) * rs * wv.w + bv.w);
    ((ushort4*)(yln + r * DD))[i4] = o;
  }
}

// ----------------------------------------------------------- fp32 -> bf16 cast
__global__ void k_cast(const float* __restrict__ src, unsigned short* __restrict__ dst, int n4) {
  int i = blockIdx.x * 256 + threadIdx.x;
  if (i < n4) {
    float4 v = ((const float4*)src)[i];
    ushort4 o;
    o.x = f2bf(v.x); o.y = f2bf(v.y); o.z = f2bf(v.z); o.w = f2bf(v.w);
    ((ushort4*)dst)[i] = o;
  }
}

// --------------- final GEMM: out = yln @ fcw^T + fcb + y  (bf16 MFMA, fp32 out)
#define GBM 128
#define GBN 128
#define GBK 32
#define LDKP 40  // padded row (bf16 units)

__global__ __launch_bounds__(256) void k_gemm(const short* __restrict__ A,
                                              const short* __restrict__ Bw,
                                              const float* __restrict__ fcb,
                                              const float* __restrict__ yy,
                                              float* __restrict__ out) {
  __shared__ short As[GBM * LDKP];
  __shared__ short Bs[GBN * LDKP];
  const int t = threadIdx.x;
  const int bm = blockIdx.x & 127;   // 16384/128
  const int bn = blockIdx.x >> 7;    // 1024/128
  const int wave = t >> 6, lane = t & 63;
  const int wr = wave >> 1, wc = wave & 1;
  const int rrow = lane & 15, kb = (lane >> 4) * 8;

  f32x4 acc[4][4];
#pragma unroll
  for (int i = 0; i < 4; ++i)
#pragma unroll
    for (int j = 0; j < 4; ++j) acc[i][j] = (f32x4){0.f, 0.f, 0.f, 0.f};

  for (int k0 = 0; k0 < 1024; k0 += GBK) {
#pragma unroll
    for (int c = 0; c < 2; ++c) {
      int chunk = c * 256 + t;             // 512 chunks of 8 bf16
      int row = chunk >> 2, off = (chunk & 3) * 8;
      s16x8 av = *(const s16x8*)(A + ((size_t)(bm * GBM + row)) * 1024 + k0 + off);
      *(s16x8*)&As[row * LDKP + off] = av;
      s16x8 bv = *(const s16x8*)(Bw + ((size_t)(bn * GBN + row)) * 1024 + k0 + off);
      *(s16x8*)&Bs[row * LDKP + off] = bv;
    }
    __syncthreads();
    s16x8 af[4], bfr[4];
#pragma unroll
    for (int mr = 0; mr < 4; ++mr)
      af[mr] = *(const s16x8*)&As[(wr * 64 + mr * 16 + rrow) * LDKP + kb];
#pragma unroll
    for (int nc = 0; nc < 4; ++nc)
      bfr[nc] = *(const s16x8*)&Bs[(wc * 64 + nc * 16 + rrow) * LDKP + kb];
#pragma unroll
    for (int mr = 0; mr < 4; ++mr)
#pragma unroll
      for (int nc = 0; nc < 4; ++nc)
        acc[mr][nc] = __builtin_amdgcn_mfma_f32_16x16x32_bf16(af[mr], bfr[nc], acc[mr][nc], 0, 0, 0);
    __syncthreads();
  }
  const int cg = lane >> 4, cr = lane & 15;
#pragma unroll
  for (int mr = 0; mr < 4; ++mr)
#pragma unroll
    for (int nc = 0; nc < 4; ++nc) {
      f32x4 a = acc[mr][nc];
      int col = bn * GBN + wc * 64 + nc * 16 + cr;
#pragma unroll
      for (int q = 0; q < 4; ++q) {
        int row = bm * GBM + wr * 64 + mr * 16 + cg * 4 + q;
        size_t idx = (size_t)row * 1024 + col;
        out[idx] = a[q] + fcb[col] + yy[idx];   // fp32 output
      }
    }
}

// ============================================================== launcher
extern "C" void kernel_launch(void* const* d_in, const int* in_sizes, int n_in,
                              void* d_out, int out_size, void* d_ws, size_t ws_size,
                              hipStream_t stream) {
  const float* u      = (const float*)d_in[0];
  const float* n1w    = (const float*)d_in[1];
  const float* n1b    = (const float*)d_in[2];
  const float* projw  = (const float*)d_in[3];
  const float* projb  = (const float*)d_in[4];
  const float* convw  = (const float*)d_in[5];
  const float* convb  = (const float*)d_in[6];
  const float* pos_t  = (const float*)d_in[7];
  const float* pos_z  = (const float*)d_in[8];
  const float* w0     = (const float*)d_in[9];
  const float* b0     = (const float*)d_in[10];
  const float* f0     = (const float*)d_in[11];
  const float* w1     = (const float*)d_in[12];
  const float* b1     = (const float*)d_in[13];
  const float* f1     = (const float*)d_in[14];
  const float* w2     = (const float*)d_in[15];
  const float* b2     = (const float*)d_in[16];
  const float* f2     = (const float*)d_in[17];
  const float* wout   = (const float*)d_in[18];
  const float* alphas = (const float*)d_in[19];
  const float* hyb    = (const float*)d_in[20];
  const float* n2w    = (const float*)d_in[21];
  const float* n2b    = (const float*)d_in[22];
  const float* fcw    = (const float*)d_in[23];
  const float* fcb    = (const float*)d_in[24];

  char* wsb = (char*)d_ws;
  size_t off = 0;
  auto alloc = [&](size_t bytes) -> void* {
    off = (off + 255) & ~(size_t)255;
    void* p = wsb + off;
    off += bytes;
    return p;
  };
  // ---- workspace layout (~135 MB total, with liveness overlays) ----
  float2* tw    = (float2*)alloc(sizeof(float2) * (NFFT / 2));
  float*  xp0   = (float*)alloc(sizeof(float) * NB * LL);
  float*  xp1   = (float*)alloc(sizeof(float) * NB * LL);
  float*  xpL   = (float*)alloc(sizeof(float) * NB * LL);
  float*  x0c   = (float*)alloc(sizeof(float) * NB * LL);
  float*  x1c   = (float*)alloc(sizeof(float) * NB * LL);
  float*  xLc   = (float*)alloc(sizeof(float) * NB * LL);
  float*  hid2T = (float*)alloc(sizeof(float) * 64 * LL);                 // 1 MB
  float2* Hs    = (float2*)alloc(sizeof(float2) * 2 * DD * KBINS);        // 67.1 MB
  float2* V0s   = (float2*)alloc(sizeof(float2) * NB * KBINS);
  float*  v1    = (float*)alloc(sizeof(float) * NB * DD * LL);            // 64 MB
  unsigned short* fcwb = (unsigned short*)alloc(sizeof(unsigned short) * DD * DD);
  // overlays: Hs dead after k_conv2 -> reuse as y; v1 dead after transpose -> reuse as yln
  float*          y   = (float*)Hs;            // 64 MB needed, 67.1 MB available
  unsigned short* yln = (unsigned short*)v1;   // 32 MB needed, 64 MB available
  (void)ws_size; (void)in_sizes; (void)n_in; (void)out_size;

  k_twiddle<<<16, 256, 0, stream>>>(tw);
  k_ln_proj<<<(NB * LL) / 4, 256, 0, stream>>>(u, n1w, n1b, projw, projb, xp0, xp1, xpL);
  k_tapconv<<<(NB * LL) / 256, 256, 0, stream>>>(xp0, xp1, xpL, convw, convb, x0c, x1c, xLc);
  k_ffn_hidden<<<LL / 16, 256, 0, stream>>>(pos_z, w0, b0, f0, w1, b1, f1, w2, b2, f2, hid2T);
  k_fft_filters<<<1024, 256, 0, stream>>>(hid2T, wout, alphas, pos_t, Hs, tw);
  k_fft_v0<<<2, 256, 0, stream>>>(xLc, V0s, tw);
  k_conv1<<<2048, 256, 0, stream>>>(Hs, V0s, x0c, xLc, hyb, v1, tw);
  k_conv2<<<2048, 256, 0, stream>>>(Hs + (size_t)DD * KBINS, x1c, v1, hyb + DD, tw);
  k_transpose_add<<<4096, 256, 0, stream>>>(v1, u, y);
  k_ln2<<<(NB * LL) / 4, 256, 0, stream>>>(y, n2w, n2b, yln);
  k_cast<<<(DD * DD / 4) / 256, 256, 0, stream>>>(fcw, fcwb, DD * DD / 4);
  k_gemm<<<(16384 / GBM) * (1024 / GBN), 256, 0, stream>>>((const short*)yln, (const short*)fcwb,
                                                           fcb, y, (float*)d_out);
}

// Round 4
// 566.387 us; speedup vs baseline: 2.3139x; 2.3139x over previous
//
#include <hip/hip_runtime.h>
#include <hip/hip_bf16.h>

#define LL 4096
#define DD 1024
#define NB 4
#define NFFT 8192
#define LOGN 13
#define KBINS 4097
#define NSLOT 8454   // SLT(8191)+1
#define PI_F 3.14159265358979323846f

typedef __attribute__((ext_vector_type(4))) float f32x4;
typedef __attribute__((ext_vector_type(8))) short s16x8;

__device__ __forceinline__ unsigned short f2bf(float f) {
  unsigned int x = __float_as_uint(f);
  x += 0x7fffu + ((x >> 16) & 1u);
  return (unsigned short)(x >> 16);
}

// padded LDS slot: breaks the stride-128 bit-reversal bank conflict (64-way -> ~4-way)
__device__ __forceinline__ int SLT(int n) { return n + (n >> 5) + (n >> 10); }

__device__ __forceinline__ float2 cmul(float2 a, float2 b) {
  return make_float2(a.x * b.x - a.y * b.y, a.x * b.y + a.y * b.x);
}

// ---------------------------------------------------------------- twiddles
__global__ void k_twiddle(float2* tw) {
  int k = blockIdx.x * 256 + threadIdx.x;
  if (k < NFFT / 2) {
    float ang = -2.0f * PI_F * (float)k / (float)NFFT;
    float s, c;
    sincosf(ang, &s, &c);
    tw[k] = make_float2(c, s);  // e^{-2pi i k / N}
  }
}

// ------------------- 8192-pt FFT core: radix-4 passes, 512 threads, swizzled LDS
// input must be in bit-reversed slot order; output natural order (DIT).
template<bool INV>
__device__ __forceinline__ void fft_passes(float2* Z, const float2* __restrict__ tw) {
  const int tid = threadIdx.x;
#pragma unroll
  for (int p = 0; p < 6; ++p) {
    const int hs = 2 * p;
    const int h = 1 << hs;
#pragma unroll
    for (int gi = 0; gi < 4; ++gi) {
      int g = tid + gi * 512;
      int j0 = g & (h - 1);
      int i = ((g >> hs) << (hs + 2)) + j0;
      int s0 = SLT(i), s1 = SLT(i + h), s2 = SLT(i + 2 * h), s3 = SLT(i + 3 * h);
      float2 a = Z[s0], b = Z[s1], c = Z[s2], d = Z[s3];
      float2 t1 = tw[j0 << (12 - hs)];
      float2 t2 = tw[j0 << (11 - hs)];
      if (INV) { t1.y = -t1.y; t2.y = -t2.y; }
      float2 t3 = INV ? make_float2(-t2.y, t2.x) : make_float2(t2.y, -t2.x);
      float2 tb = cmul(t1, b), td = cmul(t1, d);
      float2 a1 = make_float2(a.x + tb.x, a.y + tb.y);
      float2 b1 = make_float2(a.x - tb.x, a.y - tb.y);
      float2 c1 = make_float2(c.x + td.x, c.y + td.y);
      float2 d1 = make_float2(c.x - td.x, c.y - td.y);
      float2 tc = cmul(t2, c1), te = cmul(t3, d1);
      Z[s0] = make_float2(a1.x + tc.x, a1.y + tc.y);
      Z[s2] = make_float2(a1.x - tc.x, a1.y - tc.y);
      Z[s1] = make_float2(b1.x + te.x, b1.y + te.y);
      Z[s3] = make_float2(b1.x - te.x, b1.y - te.y);
    }
    __syncthreads();
  }
  // final radix-2 stage (half = 4096)
#pragma unroll
  for (int gi = 0; gi < 8; ++gi) {
    int t = tid + gi * 512;
    int s0 = SLT(t), s1 = SLT(t + 4096);
    float2 w = tw[t];
    if (INV) w.y = -w.y;
    float2 a = Z[s0], b = Z[s1];
    float2 tb = cmul(w, b);
    Z[s0] = make_float2(a.x + tb.x, a.y + tb.y);
    Z[s1] = make_float2(a.x - tb.x, a.y - tb.y);
  }
  __syncthreads();
}

__device__ __forceinline__ void bitrev_inplace(float2* Z) {
#pragma unroll
  for (int gi = 0; gi < 16; ++gi) {
    int t = threadIdx.x + gi * 512;
    int r = (int)(__brev((unsigned)t) >> 19);
    if (r > t) {
      int st = SLT(t), sr = SLT(r);
      float2 a = Z[st];
      Z[st] = Z[sr];
      Z[sr] = a;
    }
  }
  __syncthreads();
}

// ------------------------------------------- LN1 + 3-channel projection (wave/row)
__global__ __launch_bounds__(256) void k_ln_proj(
    const float* __restrict__ u, const float* __restrict__ n1w, const float* __restrict__ n1b,
    const float* __restrict__ pw, const float* __restrict__ pb,
    float* __restrict__ xp0, float* __restrict__ xp1, float* __restrict__ xpL) {
  const int wid = threadIdx.x >> 6, lane = threadIdx.x & 63;
  const int r = blockIdx.x * 4 + wid;
  const float* ur = u + (size_t)r * DD;
  float4 uv[4];
  float s = 0.f, sq = 0.f;
#pragma unroll
  for (int c = 0; c < 4; ++c) {
    uv[c] = ((const float4*)ur)[lane + 64 * c];
    s += uv[c].x + uv[c].y + uv[c].z + uv[c].w;
    sq += uv[c].x * uv[c].x + uv[c].y * uv[c].y + uv[c].z * uv[c].z + uv[c].w * uv[c].w;
  }
  for (int m = 1; m < 64; m <<= 1) { s += __shfl_xor(s, m); sq += __shfl_xor(sq, m); }
  const float mean = s * (1.0f / DD);
  const float var = sq * (1.0f / DD) - mean * mean;
  const float rs = rsqrtf(var + 1e-5f);
  float d0 = 0.f, d1 = 0.f, dL = 0.f;
  const float* pwL = pw + (size_t)3071 * DD;
#pragma unroll
  for (int c = 0; c < 4; ++c) {
    int i4 = lane + 64 * c;
    float4 wv = ((const float4*)n1w)[i4];
    float4 bv = ((const float4*)n1b)[i4];
    float4 p0 = ((const float4*)pw)[i4];
    float4 p1v = ((const float4*)(pw + DD))[i4];
    float4 pLv = ((const float4*)pwL)[i4];
    float xn;
    xn = (uv[c].x - mean) * rs * wv.x + bv.x; d0 += xn * p0.x; d1 += xn * p1v.x; dL += xn * pLv.x;
    xn = (uv[c].y - mean) * rs * wv.y + bv.y; d0 += xn * p0.y; d1 += xn * p1v.y; dL += xn * pLv.y;
    xn = (uv[c].z - mean) * rs * wv.z + bv.z; d0 += xn * p0.z; d1 += xn * p1v.z; dL += xn * pLv.z;
    xn = (uv[c].w - mean) * rs * wv.w + bv.w; d0 += xn * p0.w; d1 += xn * p1v.w; dL += xn * pLv.w;
  }
  for (int m = 1; m < 64; m <<= 1) {
    d0 += __shfl_xor(d0, m); d1 += __shfl_xor(d1, m); dL += __shfl_xor(dL, m);
  }
  if (lane == 0) {
    xp0[r] = d0 + pb[0];
    xp1[r] = d1 + pb[1];
    xpL[r] = dL + pb[3071];
  }
}

// ------------------------------------------------------- 3-tap causal depthwise conv
__global__ __launch_bounds__(256) void k_tapconv(
    const float* __restrict__ xp0, const float* __restrict__ xp1, const float* __restrict__ xpL,
    const float* __restrict__ cw, const float* __restrict__ cb,
    float* __restrict__ x0c, float* __restrict__ x1c, float* __restrict__ xLc) {
  int idx = blockIdx.x * 256 + threadIdx.x;
  if (idx >= NB * LL) return;
  int l = idx & (LL - 1);
  int base = idx - l;
  {
    const float* a = xp0 + base;
    float v = cw[2] * a[l];
    if (l >= 1) v += cw[1] * a[l - 1];
    if (l >= 2) v += cw[0] * a[l - 2];
    x0c[idx] = v + cb[0];
  }
  {
    const float* a = xp1 + base;
    float v = cw[5] * a[l];
    if (l >= 1) v += cw[4] * a[l - 1];
    if (l >= 2) v += cw[3] * a[l - 2];
    x1c[idx] = v + cb[1];
  }
  {
    const float* a = xpL + base;
    float v = cw[3071 * 3 + 2] * a[l];
    if (l >= 1) v += cw[3071 * 3 + 1] * a[l - 1];
    if (l >= 2) v += cw[3071 * 3 + 0] * a[l - 2];
    xLc[idx] = v + cb[3071];
  }
}

// ---------------------- SIREN FFN hidden states only -> hid2T[64][LL]  (1 MB)
__global__ __launch_bounds__(256) void k_ffn_hidden(
    const float* __restrict__ pos_z,
    const float* __restrict__ w0, const float* __restrict__ b0, const float* __restrict__ f0,
    const float* __restrict__ w1, const float* __restrict__ b1, const float* __restrict__ f1,
    const float* __restrict__ w2, const float* __restrict__ b2, const float* __restrict__ f2,
    float* __restrict__ hid2T) {
  __shared__ float zin[4][66];
  __shared__ float hbuf[4][64];
  const int g = threadIdx.x >> 6, lane = threadIdx.x & 63;
  const int l0 = blockIdx.x * 16;
  for (int it = 0; it < 4; ++it) {
    const int l = l0 + g * 4 + it;
    zin[g][lane] = pos_z[(size_t)l * 65 + lane];
    if (lane == 0) zin[g][64] = pos_z[(size_t)l * 65 + 64];
    __syncthreads();
    float acc = b0[lane];
#pragma unroll
    for (int k = 0; k < 65; ++k) acc += zin[g][k] * w0[lane * 65 + k];
    float hv = sinf(f0[lane] * acc);
    __syncthreads();
    hbuf[g][lane] = hv;
    __syncthreads();
    acc = b1[lane];
#pragma unroll
    for (int k = 0; k < 64; ++k) acc += hbuf[g][k] * w1[lane * 64 + k];
    hv = sinf(f1[lane] * acc);
    __syncthreads();
    hbuf[g][lane] = hv;
    __syncthreads();
    acc = b2[lane];
#pragma unroll
    for (int k = 0; k < 64; ++k) acc += hbuf[g][k] * w2[lane * 64 + k];
    hv = sinf(f2[lane] * acc);
    hid2T[(size_t)lane * LL + l] = hv;
    __syncthreads();
  }
}

// ----- filter gen (wout proj + decay) fused with fwd FFT (two-for-one) -> spectra
// order 0: store (Ha, Hb) = per-channel spectra. order 1: store P=(Ha+Hb)/2, Q=(Ha-Hb)/2.
__global__ __launch_bounds__(512) void k_fft_filters(
    const float* __restrict__ hid2T, const float* __restrict__ wout,
    const float* __restrict__ alphas, const float* __restrict__ pos_t,
    float2* __restrict__ Hs, const float2* __restrict__ tw) {
  __shared__ float2 Z[NSLOT];
  __shared__ float wdL[64], weL[64];
  const int i = blockIdx.x >> 9, c = blockIdx.x & 511;
  const int d = 2 * c, e = d + 1;
  const int tid = threadIdx.x;
  if (tid < 64) wdL[tid] = wout[(size_t)(i * DD + d) * 64 + tid];
  else if (tid < 128) weL[tid - 64] = wout[(size_t)(i * DD + e) * 64 + (tid - 64)];
  __syncthreads();
  const float ad = alphas[d], ae = alphas[e];
#pragma unroll
  for (int gi = 0; gi < 8; ++gi) {
    int l = tid + gi * 512;
    float accd = 0.f, acce = 0.f;
#pragma unroll 16
    for (int k = 0; k < 64; ++k) {
      float hk = hid2T[(size_t)k * LL + l];
      accd = fmaf(hk, wdL[k], accd);
      acce = fmaf(hk, weL[k], acce);
    }
    float t = pos_t[l];
    float2 v = make_float2(accd * expf(ad * t), acce * expf(ae * t));
    int r = (int)(__brev((unsigned)l) >> 19);   // even slot; r+1 is the zero-pad partner
    Z[SLT(r)] = v;
    Z[SLT(r + 1)] = make_float2(0.f, 0.f);
  }
  __syncthreads();
  fft_passes<false>(Z, tw);
  float2* O1 = Hs + ((size_t)i * DD + d) * KBINS;
  float2* O2 = Hs + ((size_t)i * DD + e) * KBINS;
  for (int k = tid; k < KBINS; k += 512) {
    int m = (NFFT - k) & (NFFT - 1);
    float2 zk = Z[SLT(k)], zn = Z[SLT(m)];
    float2 A = make_float2(0.5f * (zk.x + zn.x), 0.5f * (zk.y - zn.y));
    float2 B = make_float2(0.5f * (zk.y + zn.y), 0.5f * (zn.x - zk.x));
    if (i == 0) {
      O1[k] = A;
      O2[k] = B;
    } else {
      O1[k] = make_float2(0.5f * (A.x + B.x), 0.5f * (A.y + B.y));  // P
      O2[k] = make_float2(0.5f * (A.x - B.x), 0.5f * (A.y - B.y));  // Q
    }
  }
}

// --------------------------------------------------- forward FFT of v0 (4 signals, paired)
__global__ __launch_bounds__(512) void k_fft_v0(const float* __restrict__ xLc,
                                                float2* __restrict__ V0s,
                                                const float2* __restrict__ tw) {
  __shared__ float2 Z[NSLOT];
  const int b0 = 2 * blockIdx.x, b1 = b0 + 1;
  const int tid = threadIdx.x;
#pragma unroll
  for (int gi = 0; gi < 8; ++gi) {
    int n = tid + gi * 512;
    float2 v = make_float2(xLc[(size_t)b0 * LL + n], xLc[(size_t)b1 * LL + n]);
    int r = (int)(__brev((unsigned)n) >> 19);
    Z[SLT(r)] = v;
    Z[SLT(r + 1)] = make_float2(0.f, 0.f);
  }
  __syncthreads();
  fft_passes<false>(Z, tw);
  float2* Va = V0s + (size_t)b0 * KBINS;
  float2* Vb = V0s + (size_t)b1 * KBINS;
  for (int k = tid; k < KBINS; k += 512) {
    int m = (NFFT - k) & (NFFT - 1);
    float2 zk = Z[SLT(k)], zn = Z[SLT(m)];
    Va[k] = make_float2(0.5f * (zk.x + zn.x), 0.5f * (zk.y - zn.y));
    Vb[k] = make_float2(0.5f * (zk.y + zn.y), 0.5f * (zn.x - zk.x));
  }
}

// ---------- fused conv1+conv2: product1 -> iFFT -> gate1 -> FFT -> product2 -> iFFT -> gate2
__global__ __launch_bounds__(512) void k_conv12(
    const float2* __restrict__ Hs, const float2* __restrict__ V0s,
    const float* __restrict__ x0c, const float* __restrict__ x1c, const float* __restrict__ xLc,
    const float* __restrict__ hyb, float* __restrict__ v2, const float2* __restrict__ tw) {
  __shared__ float2 Z[NSLOT];
  const int b = blockIdx.x >> 9, c = blockIdx.x & 511;
  const int d = 2 * c, e = d + 1;
  const int tid = threadIdx.x;
  const float2* Ha = Hs + (size_t)d * KBINS;
  const float2* Hb = Hs + (size_t)e * KBINS;
  const float2* V = V0s + (size_t)b * KBINS;
  // product1: W = V*(Hd + i He), scatter-write in bit-reversed slots
  for (int k = tid; k < KBINS; k += 512) {
    float2 v = V[k], hd = Ha[k], he = Hb[k];
    float pr = v.x * hd.x - v.y * hd.y, pi = v.x * hd.y + v.y * hd.x;
    float qr = v.x * he.x - v.y * he.y, qi = v.x * he.y + v.y * he.x;
    int rk = (int)(__brev((unsigned)k) >> 19);
    Z[SLT(rk)] = make_float2(pr - qi, pi + qr);
    if (k > 0 && k < NFFT / 2) {
      int rm = (int)(__brev((unsigned)(NFFT - k)) >> 19);
      Z[SLT(rm)] = make_float2(pr + qi, qr - pi);
    }
  }
  __syncthreads();
  fft_passes<true>(Z, tw);  // inverse -> natural order
  // gate1 (+ zero upper half); stash v1 in registers for gate2's bias term
  const float bd0 = hyb[d], be0 = hyb[e];
  const float inv = 1.0f / NFFT;
  const float* g0 = x0c + (size_t)b * LL;
  const float* vv0 = xLc + (size_t)b * LL;
  float2 vsave[8];
#pragma unroll
  for (int gi = 0; gi < 8; ++gi) {
    int n = tid + gi * 512;
    float2 w = Z[SLT(n)];
    float vv = vv0[n], gg = g0[n];
    float2 r = make_float2(gg * fmaf(w.x, inv, bd0 * vv),
                           gg * fmaf(w.y, inv, be0 * vv));
    vsave[gi] = r;
    Z[SLT(n)] = r;
    Z[SLT(n + 4096)] = make_float2(0.f, 0.f);
  }
  __syncthreads();
  bitrev_inplace(Z);
  fft_passes<false>(Z, tw);  // forward -> natural spectrum
  // product2 in place: W[k] = P*zk + Q*conj(zn); W[m] = conj(P)*zn + conj(Q*zk)
  const float2* Pp = Hs + ((size_t)DD + d) * KBINS;
  const float2* Qq = Hs + ((size_t)DD + e) * KBINS;
  for (int k = tid; k < KBINS; k += 512) {
    int m = (NFFT - k) & (NFFT - 1);
    float2 zk = Z[SLT(k)], zn = Z[SLT(m)];
    float2 P = Pp[k], Q = Qq[k];
    float2 wk = make_float2(P.x * zk.x - P.y * zk.y + Q.x * zn.x + Q.y * zn.y,
                            P.x * zk.y + P.y * zk.x - Q.x * zn.y + Q.y * zn.x);
    Z[SLT(k)] = wk;
    if (k > 0 && k < NFFT / 2) {
      float2 wm = make_float2(P.x * zn.x + P.y * zn.y + Q.x * zk.x - Q.y * zk.y,
                              P.x * zn.y - P.y * zn.x - Q.x * zk.y - Q.y * zk.x);
      Z[SLT(m)] = wm;
    }
  }
  __syncthreads();
  bitrev_inplace(Z);
  fft_passes<true>(Z, tw);  // inverse -> natural order
  // gate2 + store v2
  const float bd1 = hyb[DD + d], be1 = hyb[DD + e];
  const float* g1 = x1c + (size_t)b * LL;
  float* vd = v2 + ((size_t)b * DD + d) * LL;
  float* ve = v2 + ((size_t)b * DD + e) * LL;
#pragma unroll
  for (int gi = 0; gi < 8; ++gi) {
    int n = tid + gi * 512;
    float2 w = Z[SLT(n)];
    float gg = g1[n];
    vd[n] = gg * fmaf(w.x, inv, bd1 * vsave[gi].x);
    ve[n] = gg * fmaf(w.y, inv, be1 * vsave[gi].y);
  }
}

// -------------------------------------------- y[b][l][d] = u + v2^T (LDS tile transpose)
__global__ __launch_bounds__(256) void k_transpose_add(const float* __restrict__ v2,
                                                       const float* __restrict__ u,
                                                       float* __restrict__ y) {
  __shared__ float T[64][65];
  const int bid = blockIdx.x;
  const int lt = bid & 63, dt = (bid >> 6) & 15, b = bid >> 10;
  const int t = threadIdx.x;
  const int tdr = t >> 2, lc0 = (t & 3) * 16;
  const float* vp = v2 + ((size_t)(b * DD + dt * 64 + tdr)) * LL + lt * 64 + lc0;
#pragma unroll
  for (int q = 0; q < 4; ++q) {
    float4 vv = ((const float4*)vp)[q];
    T[tdr][lc0 + 4 * q + 0] = vv.x;
    T[tdr][lc0 + 4 * q + 1] = vv.y;
    T[tdr][lc0 + 4 * q + 2] = vv.z;
    T[tdr][lc0 + 4 * q + 3] = vv.w;
  }
  __syncthreads();
  const int dc = t & 63, lg = t >> 6;
#pragma unroll
  for (int lr0 = 0; lr0 < 64; lr0 += 4) {
    int lr = lr0 + lg;
    size_t idx = ((size_t)b * LL + lt * 64 + lr) * DD + dt * 64 + dc;
    y[idx] = u[idx] + T[dc][lr];
  }
}

// ----------------------------------------------------- LN2 -> bf16 (wave per row)
__global__ __launch_bounds__(256) void k_ln2(const float* __restrict__ y,
                                             const float* __restrict__ w,
                                             const float* __restrict__ bb,
                                             unsigned short* __restrict__ yln) {
  const int wid = threadIdx.x >> 6, lane = threadIdx.x & 63;
  const size_t r = (size_t)blockIdx.x * 4 + wid;
  const float* yr = y + r * DD;
  float4 v[4];
  float s = 0.f, sq = 0.f;
#pragma unroll
  for (int c = 0; c < 4; ++c) {
    v[c] = ((const float4*)yr)[lane + 64 * c];
    s += v[c].x + v[c].y + v[c].z + v[c].w;
    sq += v[c].x * v[c].x + v[c].y * v[c].y + v[c].z * v[c].z + v[c].w * v[c].w;
  }
  for (int m = 1; m < 64; m <<= 1) { s += __shfl_xor(s, m); sq += __shfl_xor(sq, m); }
  const float mean = s * (1.0f / DD);
  const float var = sq * (1.0f / DD) - mean * mean;
  const float rs = rsqrtf(var + 1e-5f);
#pragma unroll
  for (int c = 0; c < 4; ++c) {
    int i4 = lane + 64 * c;
    float4 wv = ((const float4*)w)[i4];
    float4 bv = ((const float4*)bb)[i4];
    ushort4 o;
    o.x = f2bf((v[c].x - mean) * rs * wv.x + bv.x);
    o.y = f2bf((v[c].y - mean) * rs * wv.y + bv.y);
    o.z = f2bf((v[c].z - mean) * rs * wv.z + bv.z);
    o.w = f2bf((v[c].w - mean) * rs * wv.w + bv.w);
    ((ushort4*)(yln + r * DD))[i4] = o;
  }
}

// ----------------------------------------------------------- fp32 -> bf16 cast
__global__ void k_cast(const float* __restrict__ src, unsigned short* __restrict__ dst, int n4) {
  int i = blockIdx.x * 256 + threadIdx.x;
  if (i < n4) {
    float4 v = ((const float4*)src)[i];
    ushort4 o;
    o.x = f2bf(v.x); o.y = f2bf(v.y); o.z = f2bf(v.z); o.w = f2bf(v.w);
    ((ushort4*)dst)[i] = o;
  }
}

// --------------- final GEMM: out = yln @ fcw^T + fcb + y  (bf16 MFMA, fp32 out)
#define GBM 128
#define GBN 128
#define GBK 32
#define LDKP 40

__global__ __launch_bounds__(256) void k_gemm(const short* __restrict__ A,
                                              const short* __restrict__ Bw,
                                              const float* __restrict__ fcb,
                                              const float* __restrict__ yy,
                                              float* __restrict__ out) {
  __shared__ short As[GBM * LDKP];
  __shared__ short Bs[GBN * LDKP];
  const int t = threadIdx.x;
  const int bm = blockIdx.x & 127;
  const int bn = blockIdx.x >> 7;
  const int wave = t >> 6, lane = t & 63;
  const int wr = wave >> 1, wc = wave & 1;
  const int rrow = lane & 15, kb = (lane >> 4) * 8;

  f32x4 acc[4][4];
#pragma unroll
  for (int i = 0; i < 4; ++i)
#pragma unroll
    for (int j = 0; j < 4; ++j) acc[i][j] = (f32x4){0.f, 0.f, 0.f, 0.f};

  for (int k0 = 0; k0 < 1024; k0 += GBK) {
#pragma unroll
    for (int c = 0; c < 2; ++c) {
      int chunk = c * 256 + t;
      int row = chunk >> 2, off = (chunk & 3) * 8;
      s16x8 av = *(const s16x8*)(A + ((size_t)(bm * GBM + row)) * 1024 + k0 + off);
      *(s16x8*)&As[row * LDKP + off] = av;
      s16x8 bv = *(const s16x8*)(Bw + ((size_t)(bn * GBN + row)) * 1024 + k0 + off);
      *(s16x8*)&Bs[row * LDKP + off] = bv;
    }
    __syncthreads();
    s16x8 af[4], bfr[4];
#pragma unroll
    for (int mr = 0; mr < 4; ++mr)
      af[mr] = *(const s16x8*)&As[(wr * 64 + mr * 16 + rrow) * LDKP + kb];
#pragma unroll
    for (int nc = 0; nc < 4; ++nc)
      bfr[nc] = *(const s16x8*)&Bs[(wc * 64 + nc * 16 + rrow) * LDKP + kb];
#pragma unroll
    for (int mr = 0; mr < 4; ++mr)
#pragma unroll
      for (int nc = 0; nc < 4; ++nc)
        acc[mr][nc] = __builtin_amdgcn_mfma_f32_16x16x32_bf16(af[mr], bfr[nc], acc[mr][nc], 0, 0, 0);
    __syncthreads();
  }
  const int cg = lane >> 4, cr = lane & 15;
#pragma unroll
  for (int mr = 0; mr < 4; ++mr)
#pragma unroll
    for (int nc = 0; nc < 4; ++nc) {
      f32x4 a = acc[mr][nc];
      int col = bn * GBN + wc * 64 + nc * 16 + cr;
#pragma unroll
      for (int q = 0; q < 4; ++q) {
        int row = bm * GBM + wr * 64 + mr * 16 + cg * 4 + q;
        size_t idx = (size_t)row * 1024 + col;
        out[idx] = a[q] + fcb[col] + yy[idx];
      }
    }
}

// ============================================================== launcher
extern "C" void kernel_launch(void* const* d_in, const int* in_sizes, int n_in,
                              void* d_out, int out_size, void* d_ws, size_t ws_size,
                              hipStream_t stream) {
  const float* u      = (const float*)d_in[0];
  const float* n1w    = (const float*)d_in[1];
  const float* n1b    = (const float*)d_in[2];
  const float* projw  = (const float*)d_in[3];
  const float* projb  = (const float*)d_in[4];
  const float* convw  = (const float*)d_in[5];
  const float* convb  = (const float*)d_in[6];
  const float* pos_t  = (const float*)d_in[7];
  const float* pos_z  = (const float*)d_in[8];
  const float* w0     = (const float*)d_in[9];
  const float* b0     = (const float*)d_in[10];
  const float* f0     = (const float*)d_in[11];
  const float* w1     = (const float*)d_in[12];
  const float* b1     = (const float*)d_in[13];
  const float* f1     = (const float*)d_in[14];
  const float* w2     = (const float*)d_in[15];
  const float* b2     = (const float*)d_in[16];
  const float* f2     = (const float*)d_in[17];
  const float* wout   = (const float*)d_in[18];
  const float* alphas = (const float*)d_in[19];
  const float* hyb    = (const float*)d_in[20];
  const float* n2w    = (const float*)d_in[21];
  const float* n2b    = (const float*)d_in[22];
  const float* fcw    = (const float*)d_in[23];
  const float* fcb    = (const float*)d_in[24];

  char* wsb = (char*)d_ws;
  size_t off = 0;
  auto alloc = [&](size_t bytes) -> void* {
    off = (off + 255) & ~(size_t)255;
    void* p = wsb + off;
    off += bytes;
    return p;
  };
  float2* tw    = (float2*)alloc(sizeof(float2) * (NFFT / 2));
  float*  xp0   = (float*)alloc(sizeof(float) * NB * LL);
  float*  xp1   = (float*)alloc(sizeof(float) * NB * LL);
  float*  xpL   = (float*)alloc(sizeof(float) * NB * LL);
  float*  x0c   = (float*)alloc(sizeof(float) * NB * LL);
  float*  x1c   = (float*)alloc(sizeof(float) * NB * LL);
  float*  xLc   = (float*)alloc(sizeof(float) * NB * LL);
  float*  hid2T = (float*)alloc(sizeof(float) * 64 * LL);
  float2* Hs    = (float2*)alloc(sizeof(float2) * 2 * DD * KBINS);   // 67.1 MB
  float2* V0s   = (float2*)alloc(sizeof(float2) * NB * KBINS);
  float*  v2    = (float*)alloc(sizeof(float) * NB * DD * LL);       // 64 MB
  unsigned short* fcwb = (unsigned short*)alloc(sizeof(unsigned short) * DD * DD);
  float*          y   = (float*)Hs;           // overlay: Hs dead after k_conv12
  unsigned short* yln = (unsigned short*)v2;  // overlay: v2 dead after transpose
  (void)ws_size; (void)in_sizes; (void)n_in; (void)out_size;

  k_twiddle<<<16, 256, 0, stream>>>(tw);
  k_ln_proj<<<(NB * LL) / 4, 256, 0, stream>>>(u, n1w, n1b, projw, projb, xp0, xp1, xpL);
  k_tapconv<<<(NB * LL) / 256, 256, 0, stream>>>(xp0, xp1, xpL, convw, convb, x0c, x1c, xLc);
  k_ffn_hidden<<<LL / 16, 256, 0, stream>>>(pos_z, w0, b0, f0, w1, b1, f1, w2, b2, f2, hid2T);
  k_fft_filters<<<1024, 512, 0, stream>>>(hid2T, wout, alphas, pos_t, Hs, tw);
  k_fft_v0<<<2, 512, 0, stream>>>(xLc, V0s, tw);
  k_conv12<<<2048, 512, 0, stream>>>(Hs, V0s, x0c, x1c, xLc, hyb, v2, tw);
  k_transpose_add<<<4096, 256, 0, stream>>>(v2, u, y);
  k_ln2<<<(NB * LL) / 4, 256, 0, stream>>>(y, n2w, n2b, yln);
  k_cast<<<(DD * DD / 4) / 256, 256, 0, stream>>>(fcw, fcwb, DD * DD / 4);
  k_gemm<<<(16384 / GBM) * (1024 / GBN), 256, 0, stream>>>((const short*)yln, (const short*)fcwb,
                                                           fcb, y, (float*)d_out);
}

// Round 5
// 473.661 us; speedup vs baseline: 2.7669x; 1.1958x over previous
//
#include <hip/hip_runtime.h>
#include <hip/hip_bf16.h>

#define LL 4096
#define DD 1024
#define NB 4
#define NFFT 8192
#define LOGN 13
#define KBINS 4097
#define NSLOT 8454   // SLT(8191)+1
#define PI_F 3.14159265358979323846f

typedef __attribute__((ext_vector_type(4))) float f32x4;
typedef __attribute__((ext_vector_type(8))) short s16x8;

__device__ __forceinline__ unsigned short f2bf(float f) {
  unsigned int x = __float_as_uint(f);
  x += 0x7fffu + ((x >> 16) & 1u);
  return (unsigned short)(x >> 16);
}

// padded LDS slot: breaks power-of-2-stride bank conflicts
__device__ __forceinline__ int SLT(int n) { return n + (n >> 5) + (n >> 10); }

__device__ __forceinline__ float2 cmul(float2 a, float2 b) {
  return make_float2(a.x * b.x - a.y * b.y, a.x * b.y + a.y * b.x);
}
__device__ __forceinline__ float2 cadd(float2 a, float2 b) { return make_float2(a.x + b.x, a.y + b.y); }
__device__ __forceinline__ float2 csub(float2 a, float2 b) { return make_float2(a.x - b.x, a.y - b.y); }
__device__ __forceinline__ float2 mulni(float2 v) { return make_float2(v.y, -v.x); }   // * -i
__device__ __forceinline__ float2 mulpi(float2 v) { return make_float2(-v.y, v.x); }   // * +i

// ---------------------------------------------------------------- twiddles
__global__ void k_twiddle(float2* tw) {
  int k = blockIdx.x * 256 + threadIdx.x;
  if (k < NFFT / 2) {
    float ang = -2.0f * PI_F * (float)k / (float)NFFT;
    float s, c;
    sincosf(ang, &s, &c);
    tw[k] = make_float2(c, s);  // e^{-2pi i k / N}
  }
}

// ---- 8192-pt FFT core: 4 radix-8 passes + 1 radix-2, 1024 threads, padded LDS.
// Input in bit-reversed slot order; output natural order (DIT).
template<bool INV>
__device__ __forceinline__ void fft_passes(float2* Z, const float2* __restrict__ tw) {
  const int tid = threadIdx.x;
  const float C8 = 0.70710678118654752f;
#pragma unroll
  for (int p = 0; p < 4; ++p) {
    const int hs = 3 * p;
    const int h = 1 << hs;
    const int j0 = tid & (h - 1);
    const int i = ((tid >> hs) << (hs + 3)) + j0;
    int s0 = SLT(i),         s1 = SLT(i + h),     s2 = SLT(i + 2 * h), s3 = SLT(i + 3 * h);
    int s4 = SLT(i + 4 * h), s5 = SLT(i + 5 * h), s6 = SLT(i + 6 * h), s7 = SLT(i + 7 * h);
    float2 a0 = Z[s0], a1 = Z[s1], a2 = Z[s2], a3 = Z[s3];
    float2 a4 = Z[s4], a5 = Z[s5], a6 = Z[s6], a7 = Z[s7];
    float2 w1 = tw[j0 << (12 - hs)];
    float2 w2 = tw[j0 << (11 - hs)];
    float2 w3 = tw[j0 << (10 - hs)];
    if (INV) { w1.y = -w1.y; w2.y = -w2.y; w3.y = -w3.y; }
    float2 t;
    // stage 1 (half = h)
    t = cmul(w1, a1); float2 b0 = cadd(a0, t), b1 = csub(a0, t);
    t = cmul(w1, a3); float2 b2 = cadd(a2, t), b3 = csub(a2, t);
    t = cmul(w1, a5); float2 b4 = cadd(a4, t), b5 = csub(a4, t);
    t = cmul(w1, a7); float2 b6 = cadd(a6, t), b7 = csub(a6, t);
    // stage 2 (half = 2h)
    t = cmul(w2, b2);                       float2 c0 = cadd(b0, t), c2 = csub(b0, t);
    t = cmul(w2, b3); t = INV ? mulpi(t) : mulni(t);
    float2 c1 = cadd(b1, t), c3 = csub(b1, t);
    t = cmul(w2, b6);                       float2 c4 = cadd(b4, t), c6 = csub(b4, t);
    t = cmul(w2, b7); t = INV ? mulpi(t) : mulni(t);
    float2 c5 = cadd(b5, t), c7 = csub(b5, t);
    // stage 3 (half = 4h)
    t = cmul(w3, c4); float2 d0 = cadd(c0, t), d4 = csub(c0, t);
    float2 e1 = cmul(w3, c5);
    t = INV ? make_float2(C8 * (e1.x - e1.y), C8 * (e1.y + e1.x))
            : make_float2(C8 * (e1.x + e1.y), C8 * (e1.y - e1.x));
    float2 d1 = cadd(c1, t), d5 = csub(c1, t);
    float2 e2 = cmul(w3, c6); t = INV ? mulpi(e2) : mulni(e2);
    float2 d2 = cadd(c2, t), d6 = csub(c2, t);
    float2 e3 = cmul(w3, c7);
    t = INV ? make_float2(-C8 * (e3.x + e3.y), C8 * (e3.x - e3.y))
            : make_float2(C8 * (e3.y - e3.x), -C8 * (e3.x + e3.y));
    float2 d3 = cadd(c3, t), d7 = csub(c3, t);
    Z[s0] = d0; Z[s1] = d1; Z[s2] = d2; Z[s3] = d3;
    Z[s4] = d4; Z[s5] = d5; Z[s6] = d6; Z[s7] = d7;
    __syncthreads();
  }
  // final radix-2 (half = 4096)
#pragma unroll
  for (int gi = 0; gi < 4; ++gi) {
    int n = tid + gi * 1024;
    int s0 = SLT(n), s1 = SLT(n + 4096);
    float2 w = tw[n];
    if (INV) w.y = -w.y;
    float2 a = Z[s0], b = Z[s1];
    float2 tb = cmul(w, b);
    Z[s0] = make_float2(a.x + tb.x, a.y + tb.y);
    Z[s1] = make_float2(a.x - tb.x, a.y - tb.y);
  }
  __syncthreads();
}

// ------------------------------------------- LN1 + 3-channel projection (wave/row)
__global__ __launch_bounds__(256) void k_ln_proj(
    const float* __restrict__ u, const float* __restrict__ n1w, const float* __restrict__ n1b,
    const float* __restrict__ pw, const float* __restrict__ pb,
    float* __restrict__ xp0, float* __restrict__ xp1, float* __restrict__ xpL) {
  const int wid = threadIdx.x >> 6, lane = threadIdx.x & 63;
  const int r = blockIdx.x * 4 + wid;
  const float* ur = u + (size_t)r * DD;
  float4 uv[4];
  float s = 0.f, sq = 0.f;
#pragma unroll
  for (int c = 0; c < 4; ++c) {
    uv[c] = ((const float4*)ur)[lane + 64 * c];
    s += uv[c].x + uv[c].y + uv[c].z + uv[c].w;
    sq += uv[c].x * uv[c].x + uv[c].y * uv[c].y + uv[c].z * uv[c].z + uv[c].w * uv[c].w;
  }
  for (int m = 1; m < 64; m <<= 1) { s += __shfl_xor(s, m); sq += __shfl_xor(sq, m); }
  const float mean = s * (1.0f / DD);
  const float var = sq * (1.0f / DD) - mean * mean;
  const float rs = rsqrtf(var + 1e-5f);
  float d0 = 0.f, d1 = 0.f, dL = 0.f;
  const float* pwL = pw + (size_t)3071 * DD;
#pragma unroll
  for (int c = 0; c < 4; ++c) {
    int i4 = lane + 64 * c;
    float4 wv = ((const float4*)n1w)[i4];
    float4 bv = ((const float4*)n1b)[i4];
    float4 p0 = ((const float4*)pw)[i4];
    float4 p1v = ((const float4*)(pw + DD))[i4];
    float4 pLv = ((const float4*)pwL)[i4];
    float xn;
    xn = (uv[c].x - mean) * rs * wv.x + bv.x; d0 += xn * p0.x; d1 += xn * p1v.x; dL += xn * pLv.x;
    xn = (uv[c].y - mean) * rs * wv.y + bv.y; d0 += xn * p0.y; d1 += xn * p1v.y; dL += xn * pLv.y;
    xn = (uv[c].z - mean) * rs * wv.z + bv.z; d0 += xn * p0.z; d1 += xn * p1v.z; dL += xn * pLv.z;
    xn = (uv[c].w - mean) * rs * wv.w + bv.w; d0 += xn * p0.w; d1 += xn * p1v.w; dL += xn * pLv.w;
  }
  for (int m = 1; m < 64; m <<= 1) {
    d0 += __shfl_xor(d0, m); d1 += __shfl_xor(d1, m); dL += __shfl_xor(dL, m);
  }
  if (lane == 0) {
    xp0[r] = d0 + pb[0];
    xp1[r] = d1 + pb[1];
    xpL[r] = dL + pb[3071];
  }
}

// ------------------------------------------------------- 3-tap causal depthwise conv
__global__ __launch_bounds__(256) void k_tapconv(
    const float* __restrict__ xp0, const float* __restrict__ xp1, const float* __restrict__ xpL,
    const float* __restrict__ cw, const float* __restrict__ cb,
    float* __restrict__ x0c, float* __restrict__ x1c, float* __restrict__ xLc) {
  int idx = blockIdx.x * 256 + threadIdx.x;
  if (idx >= NB * LL) return;
  int l = idx & (LL - 1);
  int base = idx - l;
  {
    const float* a = xp0 + base;
    float v = cw[2] * a[l];
    if (l >= 1) v += cw[1] * a[l - 1];
    if (l >= 2) v += cw[0] * a[l - 2];
    x0c[idx] = v + cb[0];
  }
  {
    const float* a = xp1 + base;
    float v = cw[5] * a[l];
    if (l >= 1) v += cw[4] * a[l - 1];
    if (l >= 2) v += cw[3] * a[l - 2];
    x1c[idx] = v + cb[1];
  }
  {
    const float* a = xpL + base;
    float v = cw[3071 * 3 + 2] * a[l];
    if (l >= 1) v += cw[3071 * 3 + 1] * a[l - 1];
    if (l >= 2) v += cw[3071 * 3 + 0] * a[l - 2];
    xLc[idx] = v + cb[3071];
  }
}

// ---------------------- SIREN FFN hidden states only -> hid2T[64][LL]  (1 MB)
__global__ __launch_bounds__(256) void k_ffn_hidden(
    const float* __restrict__ pos_z,
    const float* __restrict__ w0, const float* __restrict__ b0, const float* __restrict__ f0,
    const float* __restrict__ w1, const float* __restrict__ b1, const float* __restrict__ f1,
    const float* __restrict__ w2, const float* __restrict__ b2, const float* __restrict__ f2,
    float* __restrict__ hid2T) {
  __shared__ float zin[4][66];
  __shared__ float hbuf[4][64];
  const int g = threadIdx.x >> 6, lane = threadIdx.x & 63;
  const int l0 = blockIdx.x * 16;
  for (int it = 0; it < 4; ++it) {
    const int l = l0 + g * 4 + it;
    zin[g][lane] = pos_z[(size_t)l * 65 + lane];
    if (lane == 0) zin[g][64] = pos_z[(size_t)l * 65 + 64];
    __syncthreads();
    float acc = b0[lane];
#pragma unroll
    for (int k = 0; k < 65; ++k) acc += zin[g][k] * w0[lane * 65 + k];
    float hv = sinf(f0[lane] * acc);
    __syncthreads();
    hbuf[g][lane] = hv;
    __syncthreads();
    acc = b1[lane];
#pragma unroll
    for (int k = 0; k < 64; ++k) acc += hbuf[g][k] * w1[lane * 64 + k];
    hv = sinf(f1[lane] * acc);
    __syncthreads();
    hbuf[g][lane] = hv;
    __syncthreads();
    acc = b2[lane];
#pragma unroll
    for (int k = 0; k < 64; ++k) acc += hbuf[g][k] * w2[lane * 64 + k];
    hv = sinf(f2[lane] * acc);
    hid2T[(size_t)lane * LL + l] = hv;
    __syncthreads();
  }
}

// ----- filter gen (wout proj + decay) fused with fwd FFT (two-for-one) -> spectra
// order 0: store (Ha, Hb). order 1: store P=(Ha+Hb)/2, Q=(Ha-Hb)/2.
__global__ __launch_bounds__(1024) void k_fft_filters(
    const float* __restrict__ hid2T, const float* __restrict__ wout,
    const float* __restrict__ alphas, const float* __restrict__ pos_t,
    float2* __restrict__ Hs, const float2* __restrict__ tw) {
  __shared__ float2 Z[NSLOT];
  __shared__ float wdL[64], weL[64];
  const int i = blockIdx.x >> 9, c = blockIdx.x & 511;
  const int d = 2 * c, e = d + 1;
  const int tid = threadIdx.x;
  if (tid < 64) wdL[tid] = wout[(size_t)(i * DD + d) * 64 + tid];
  else if (tid < 128) weL[tid - 64] = wout[(size_t)(i * DD + e) * 64 + (tid - 64)];
  __syncthreads();
  const float ad = alphas[d], ae = alphas[e];
#pragma unroll
  for (int gi = 0; gi < 4; ++gi) {
    int l = tid + gi * 1024;
    float accd = 0.f, acce = 0.f;
#pragma unroll 16
    for (int k = 0; k < 64; ++k) {
      float hk = hid2T[(size_t)k * LL + l];
      accd = fmaf(hk, wdL[k], accd);
      acce = fmaf(hk, weL[k], acce);
    }
    float t = pos_t[l];
    float2 v = make_float2(accd * expf(ad * t), acce * expf(ae * t));
    int r = (int)(__brev((unsigned)l) >> 19);   // even; r+1 is the zero-pad partner
    Z[SLT(r)] = v;
    Z[SLT(r + 1)] = make_float2(0.f, 0.f);
  }
  __syncthreads();
  fft_passes<false>(Z, tw);
  float2* O1 = Hs + ((size_t)i * DD + d) * KBINS;
  float2* O2 = Hs + ((size_t)i * DD + e) * KBINS;
  for (int k = tid; k < KBINS; k += 1024) {
    int m = (NFFT - k) & (NFFT - 1);
    float2 zk = Z[SLT(k)], zn = Z[SLT(m)];
    float2 A = make_float2(0.5f * (zk.x + zn.x), 0.5f * (zk.y - zn.y));
    float2 B = make_float2(0.5f * (zk.y + zn.y), 0.5f * (zn.x - zk.x));
    if (i == 0) {
      O1[k] = A;
      O2[k] = B;
    } else {
      O1[k] = make_float2(0.5f * (A.x + B.x), 0.5f * (A.y + B.y));  // P
      O2[k] = make_float2(0.5f * (A.x - B.x), 0.5f * (A.y - B.y));  // Q
    }
  }
}

// --------------------------------------------------- forward FFT of v0 (4 signals, paired)
__global__ __launch_bounds__(1024) void k_fft_v0(const float* __restrict__ xLc,
                                                 float2* __restrict__ V0s,
                                                 const float2* __restrict__ tw) {
  __shared__ float2 Z[NSLOT];
  const int b0 = 2 * blockIdx.x, b1 = b0 + 1;
  const int tid = threadIdx.x;
#pragma unroll
  for (int gi = 0; gi < 4; ++gi) {
    int n = tid + gi * 1024;
    float2 v = make_float2(xLc[(size_t)b0 * LL + n], xLc[(size_t)b1 * LL + n]);
    int r = (int)(__brev((unsigned)n) >> 19);
    Z[SLT(r)] = v;
    Z[SLT(r + 1)] = make_float2(0.f, 0.f);
  }
  __syncthreads();
  fft_passes<false>(Z, tw);
  float2* Va = V0s + (size_t)b0 * KBINS;
  float2* Vb = V0s + (size_t)b1 * KBINS;
  for (int k = tid; k < KBINS; k += 1024) {
    int m = (NFFT - k) & (NFFT - 1);
    float2 zk = Z[SLT(k)], zn = Z[SLT(m)];
    Va[k] = make_float2(0.5f * (zk.x + zn.x), 0.5f * (zk.y - zn.y));
    Vb[k] = make_float2(0.5f * (zk.y + zn.y), 0.5f * (zn.x - zk.x));
  }
}

// ---------- fused conv1+conv2, no bitrev passes (all reorders folded into scatters)
__global__ __launch_bounds__(1024) void k_conv12(
    const float2* __restrict__ Hs, const float2* __restrict__ V0s,
    const float* __restrict__ x0c, const float* __restrict__ x1c, const float* __restrict__ xLc,
    const float* __restrict__ hyb, float* __restrict__ v2, const float2* __restrict__ tw) {
  __shared__ float2 Z[NSLOT];
  const int b = blockIdx.x >> 9, c = blockIdx.x & 511;
  const int d = 2 * c, e = d + 1;
  const int tid = threadIdx.x;
  const float2* Ha = Hs + (size_t)d * KBINS;
  const float2* Hb = Hs + (size_t)e * KBINS;
  const float2* V = V0s + (size_t)b * KBINS;
  // product1: W = V*(Hd + i He), scatter into bit-reversed slots
  for (int k = tid; k < KBINS; k += 1024) {
    float2 v = V[k], hd = Ha[k], he = Hb[k];
    float pr = v.x * hd.x - v.y * hd.y, pi = v.x * hd.y + v.y * hd.x;
    float qr = v.x * he.x - v.y * he.y, qi = v.x * he.y + v.y * he.x;
    int rk = (int)(__brev((unsigned)k) >> 19);
    Z[SLT(rk)] = make_float2(pr - qi, pi + qr);
    if (k > 0 && k < NFFT / 2) {
      int rm = (int)(__brev((unsigned)(NFFT - k)) >> 19);
      Z[SLT(rm)] = make_float2(pr + qi, qr - pi);
    }
  }
  __syncthreads();
  fft_passes<true>(Z, tw);  // inverse -> natural order
  // gate1: read lower half (natural), rescatter bit-reversed with zero padding
  const float bd0 = hyb[d], be0 = hyb[e];
  const float inv = 1.0f / NFFT;
  const float* g0 = x0c + (size_t)b * LL;
  const float* vv0 = xLc + (size_t)b * LL;
  float2 vsave[4];
#pragma unroll
  for (int gi = 0; gi < 4; ++gi) {
    int n = tid + gi * 1024;
    float2 w = Z[SLT(n)];
    float vv = vv0[n], gg = g0[n];
    vsave[gi] = make_float2(gg * fmaf(w.x, inv, bd0 * vv),
                            gg * fmaf(w.y, inv, be0 * vv));
  }
  __syncthreads();
#pragma unroll
  for (int gi = 0; gi < 4; ++gi) {
    int n = tid + gi * 1024;
    int r = (int)(__brev((unsigned)n) >> 19);  // even
    Z[SLT(r)] = vsave[gi];
    Z[SLT(r + 1)] = make_float2(0.f, 0.f);
  }
  __syncthreads();
  fft_passes<false>(Z, tw);  // forward -> natural spectrum
  // product2: read natural spectrum into regs, scatter results bit-reversed
  const float2* Pp = Hs + ((size_t)DD + d) * KBINS;
  const float2* Qq = Hs + ((size_t)DD + e) * KBINS;
  float2 wkA[4], wmA[4];
#pragma unroll
  for (int j = 0; j < 4; ++j) {
    int k = tid + j * 1024;                 // in [0, 4096)
    int m = (NFFT - k) & (NFFT - 1);
    float2 zk = Z[SLT(k)], zn = Z[SLT(m)];
    float2 P = Pp[k], Q = Qq[k];
    wkA[j] = make_float2(P.x * zk.x - P.y * zk.y + Q.x * zn.x + Q.y * zn.y,
                         P.x * zk.y + P.y * zk.x - Q.x * zn.y + Q.y * zn.x);
    wmA[j] = make_float2(P.x * zn.x + P.y * zn.y + Q.x * zk.x - Q.y * zk.y,
                         P.x * zn.y - P.y * zn.x - Q.x * zk.y - Q.y * zk.x);
  }
  float2 wc4096;
  if (tid == 0) {
    float2 zc = Z[SLT(4096)];
    float2 P = Pp[4096], Q = Qq[4096];
    wc4096 = make_float2(P.x * zc.x - P.y * zc.y + Q.x * zc.x + Q.y * zc.y,
                         P.x * zc.y + P.y * zc.x - Q.x * zc.y + Q.y * zc.x);
  }
  __syncthreads();
#pragma unroll
  for (int j = 0; j < 4; ++j) {
    int k = tid + j * 1024;
    int rk = (int)(__brev((unsigned)k) >> 19);
    Z[SLT(rk)] = wkA[j];
    if (k > 0) {
      int rm = (int)(__brev((unsigned)(NFFT - k)) >> 19);
      Z[SLT(rm)] = wmA[j];
    }
  }
  if (tid == 0) Z[SLT(1)] = wc4096;  // rev(4096) = 1
  __syncthreads();
  fft_passes<true>(Z, tw);  // inverse -> natural order
  // gate2 + store v2
  const float bd1 = hyb[DD + d], be1 = hyb[DD + e];
  const float* g1 = x1c + (size_t)b * LL;
  float* vd = v2 + ((size_t)b * DD + d) * LL;
  float* ve = v2 + ((size_t)b * DD + e) * LL;
#pragma unroll
  for (int gi = 0; gi < 4; ++gi) {
    int n = tid + gi * 1024;
    float2 w = Z[SLT(n)];
    float gg = g1[n];
    vd[n] = gg * fmaf(w.x, inv, bd1 * vsave[gi].x);
    ve[n] = gg * fmaf(w.y, inv, be1 * vsave[gi].y);
  }
}

// -------------------------------------------- y[b][l][d] = u + v2^T (LDS tile transpose)
__global__ __launch_bounds__(256) void k_transpose_add(const float* __restrict__ v2,
                                                       const float* __restrict__ u,
                                                       float* __restrict__ y) {
  __shared__ float T[64][65];
  const int bid = blockIdx.x;
  const int lt = bid & 63, dt = (bid >> 6) & 15, b = bid >> 10;
  const int t = threadIdx.x;
  const int tdr = t >> 2, lc0 = (t & 3) * 16;
  const float* vp = v2 + ((size_t)(b * DD + dt * 64 + tdr)) * LL + lt * 64 + lc0;
#pragma unroll
  for (int q = 0; q < 4; ++q) {
    float4 vv = ((const float4*)vp)[q];
    T[tdr][lc0 + 4 * q + 0] = vv.x;
    T[tdr][lc0 + 4 * q + 1] = vv.y;
    T[tdr][lc0 + 4 * q + 2] = vv.z;
    T[tdr][lc0 + 4 * q + 3] = vv.w;
  }
  __syncthreads();
  const int dc = t & 63, lg = t >> 6;
#pragma unroll
  for (int lr0 = 0; lr0 < 64; lr0 += 4) {
    int lr = lr0 + lg;
    size_t idx = ((size_t)b * LL + lt * 64 + lr) * DD + dt * 64 + dc;
    y[idx] = u[idx] + T[dc][lr];
  }
}

// ----------------------------------------------------- LN2 -> bf16 (wave per row)
__global__ __launch_bounds__(256) void k_ln2(const float* __restrict__ y,
                                             const float* __restrict__ w,
                                             const float* __restrict__ bb,
                                             unsigned short* __restrict__ yln) {
  const int wid = threadIdx.x >> 6, lane = threadIdx.x & 63;
  const size_t r = (size_t)blockIdx.x * 4 + wid;
  const float* yr = y + r * DD;
  float4 v[4];
  float s = 0.f, sq = 0.f;
#pragma unroll
  for (int c = 0; c < 4; ++c) {
    v[c] = ((const float4*)yr)[lane + 64 * c];
    s += v[c].x + v[c].y + v[c].z + v[c].w;
    sq += v[c].x * v[c].x + v[c].y * v[c].y + v[c].z * v[c].z + v[c].w * v[c].w;
  }
  for (int m = 1; m < 64; m <<= 1) { s += __shfl_xor(s, m); sq += __shfl_xor(sq, m); }
  const float mean = s * (1.0f / DD);
  const float var = sq * (1.0f / DD) - mean * mean;
  const float rs = rsqrtf(var + 1e-5f);
#pragma unroll
  for (int c = 0; c < 4; ++c) {
    int i4 = lane + 64 * c;
    float4 wv = ((const float4*)w)[i4];
    float4 bv = ((const float4*)bb)[i4];
    ushort4 o;
    o.x = f2bf((v[c].x - mean) * rs * wv.x + bv.x);
    o.y = f2bf((v[c].y - mean) * rs * wv.y + bv.y);
    o.z = f2bf((v[c].z - mean) * rs * wv.z + bv.z);
    o.w = f2bf((v[c].w - mean) * rs * wv.w + bv.w);
    ((ushort4*)(yln + r * DD))[i4] = o;
  }
}

// ----------------------------------------------------------- fp32 -> bf16 cast
__global__ void k_cast(const float* __restrict__ src, unsigned short* __restrict__ dst, int n4) {
  int i = blockIdx.x * 256 + threadIdx.x;
  if (i < n4) {
    float4 v = ((const float4*)src)[i];
    ushort4 o;
    o.x = f2bf(v.x); o.y = f2bf(v.y); o.z = f2bf(v.z); o.w = f2bf(v.w);
    ((ushort4*)dst)[i] = o;
  }
}

// --------------- final GEMM: out = yln @ fcw^T + fcb + y  (bf16 MFMA, fp32 out)
#define GBM 128
#define GBN 128
#define GBK 32
#define LDKP 40

__global__ __launch_bounds__(256) void k_gemm(const short* __restrict__ A,
                                              const short* __restrict__ Bw,
                                              const float* __restrict__ fcb,
                                              const float* __restrict__ yy,
                                              float* __restrict__ out) {
  __shared__ short As[GBM * LDKP];
  __shared__ short Bs[GBN * LDKP];
  const int t = threadIdx.x;
  const int bm = blockIdx.x & 127;
  const int bn = blockIdx.x >> 7;
  const int wave = t >> 6, lane = t & 63;
  const int wr = wave >> 1, wc = wave & 1;
  const int rrow = lane & 15, kb = (lane >> 4) * 8;

  f32x4 acc[4][4];
#pragma unroll
  for (int i = 0; i < 4; ++i)
#pragma unroll
    for (int j = 0; j < 4; ++j) acc[i][j] = (f32x4){0.f, 0.f, 0.f, 0.f};

  for (int k0 = 0; k0 < 1024; k0 += GBK) {
#pragma unroll
    for (int c = 0; c < 2; ++c) {
      int chunk = c * 256 + t;
      int row = chunk >> 2, off = (chunk & 3) * 8;
      s16x8 av = *(const s16x8*)(A + ((size_t)(bm * GBM + row)) * 1024 + k0 + off);
      *(s16x8*)&As[row * LDKP + off] = av;
      s16x8 bv = *(const s16x8*)(Bw + ((size_t)(bn * GBN + row)) * 1024 + k0 + off);
      *(s16x8*)&Bs[row * LDKP + off] = bv;
    }
    __syncthreads();
    s16x8 af[4], bfr[4];
#pragma unroll
    for (int mr = 0; mr < 4; ++mr)
      af[mr] = *(const s16x8*)&As[(wr * 64 + mr * 16 + rrow) * LDKP + kb];
#pragma unroll
    for (int nc = 0; nc < 4; ++nc)
      bfr[nc] = *(const s16x8*)&Bs[(wc * 64 + nc * 16 + rrow) * LDKP + kb];
#pragma unroll
    for (int mr = 0; mr < 4; ++mr)
#pragma unroll
      for (int nc = 0; nc < 4; ++nc)
        acc[mr][nc] = __builtin_amdgcn_mfma_f32_16x16x32_bf16(af[mr], bfr[nc], acc[mr][nc], 0, 0, 0);
    __syncthreads();
  }
  const int cg = lane >> 4, cr = lane & 15;
#pragma unroll
  for (int mr = 0; mr < 4; ++mr)
#pragma unroll
    for (int nc = 0; nc < 4; ++nc) {
      f32x4 a = acc[mr][nc];
      int col = bn * GBN + wc * 64 + nc * 16 + cr;
#pragma unroll
      for (int q = 0; q < 4; ++q) {
        int row = bm * GBM + wr * 64 + mr * 16 + cg * 4 + q;
        size_t idx = (size_t)row * 1024 + col;
        out[idx] = a[q] + fcb[col] + yy[idx];
      }
    }
}

// ============================================================== launcher
extern "C" void kernel_launch(void* const* d_in, const int* in_sizes, int n_in,
                              void* d_out, int out_size, void* d_ws, size_t ws_size,
                              hipStream_t stream) {
  const float* u      = (const float*)d_in[0];
  const float* n1w    = (const float*)d_in[1];
  const float* n1b    = (const float*)d_in[2];
  const float* projw  = (const float*)d_in[3];
  const float* projb  = (const float*)d_in[4];
  const float* convw  = (const float*)d_in[5];
  const float* convb  = (const float*)d_in[6];
  const float* pos_t  = (const float*)d_in[7];
  const float* pos_z  = (const float*)d_in[8];
  const float* w0     = (const float*)d_in[9];
  const float* b0     = (const float*)d_in[10];
  const float* f0     = (const float*)d_in[11];
  const float* w1     = (const float*)d_in[12];
  const float* b1     = (const float*)d_in[13];
  const float* f1     = (const float*)d_in[14];
  const float* w2     = (const float*)d_in[15];
  const float* b2     = (const float*)d_in[16];
  const float* f2     = (const float*)d_in[17];
  const float* wout   = (const float*)d_in[18];
  const float* alphas = (const float*)d_in[19];
  const float* hyb    = (const float*)d_in[20];
  const float* n2w    = (const float*)d_in[21];
  const float* n2b    = (const float*)d_in[22];
  const float* fcw    = (const float*)d_in[23];
  const float* fcb    = (const float*)d_in[24];

  char* wsb = (char*)d_ws;
  size_t off = 0;
  auto alloc = [&](size_t bytes) -> void* {
    off = (off + 255) & ~(size_t)255;
    void* p = wsb + off;
    off += bytes;
    return p;
  };
  float2* tw    = (float2*)alloc(sizeof(float2) * (NFFT / 2));
  float*  xp0   = (float*)alloc(sizeof(float) * NB * LL);
  float*  xp1   = (float*)alloc(sizeof(float) * NB * LL);
  float*  xpL   = (float*)alloc(sizeof(float) * NB * LL);
  float*  x0c   = (float*)alloc(sizeof(float) * NB * LL);
  float*  x1c   = (float*)alloc(sizeof(float) * NB * LL);
  float*  xLc   = (float*)alloc(sizeof(float) * NB * LL);
  float*  hid2T = (float*)alloc(sizeof(float) * 64 * LL);
  float2* Hs    = (float2*)alloc(sizeof(float2) * 2 * DD * KBINS);   // 67.1 MB
  float2* V0s   = (float2*)alloc(sizeof(float2) * NB * KBINS);
  float*  v2    = (float*)alloc(sizeof(float) * NB * DD * LL);       // 64 MB
  unsigned short* fcwb = (unsigned short*)alloc(sizeof(unsigned short) * DD * DD);
  float*          y   = (float*)Hs;           // overlay: Hs dead after k_conv12
  unsigned short* yln = (unsigned short*)v2;  // overlay: v2 dead after transpose
  (void)ws_size; (void)in_sizes; (void)n_in; (void)out_size;

  k_twiddle<<<16, 256, 0, stream>>>(tw);
  k_ln_proj<<<(NB * LL) / 4, 256, 0, stream>>>(u, n1w, n1b, projw, projb, xp0, xp1, xpL);
  k_tapconv<<<(NB * LL) / 256, 256, 0, stream>>>(xp0, xp1, xpL, convw, convb, x0c, x1c, xLc);
  k_ffn_hidden<<<LL / 16, 256, 0, stream>>>(pos_z, w0, b0, f0, w1, b1, f1, w2, b2, f2, hid2T);
  k_fft_filters<<<1024, 1024, 0, stream>>>(hid2T, wout, alphas, pos_t, Hs, tw);
  k_fft_v0<<<2, 1024, 0, stream>>>(xLc, V0s, tw);
  k_conv12<<<2048, 1024, 0, stream>>>(Hs, V0s, x0c, x1c, xLc, hyb, v2, tw);
  k_transpose_add<<<4096, 256, 0, stream>>>(v2, u, y);
  k_ln2<<<(NB * LL) / 4, 256, 0, stream>>>(y, n2w, n2b, yln);
  k_cast<<<(DD * DD / 4) / 256, 256, 0, stream>>>(fcw, fcwb, DD * DD / 4);
  k_gemm<<<(16384 / GBM) * (1024 / GBN), 256, 0, stream>>>((const short*)yln, (const short*)fcwb,
                                                           fcb, y, (float*)d_out);
}